// Round 1
// baseline (149.151 us; speedup 1.0000x reference)
//
#include <hip/hip_runtime.h>

// MoE dense: N=16384, D=256, E=8, H=128.
// R9: fuse stage1+stage2 into one persistent-tile kernel. The hw intermediate
// (69 MB HBM write + re-read) and stage1's 16x re-fetch of xb were the
// dominant remaining traffic. New k_moe: 256 blocks x 512 thr, 64 rows/block;
// x-tile LDS-resident (loaded once, reused by 8 experts), per-expert H tile
// computed TRANSPOSED (mfma(W1,x) -> C[h,n]) so the relu*g epilogue writes
// ds_write_b64 directly in the A-frag layout GEMM2 reads; out accumulated in
// registers across experts; g*b2 bias folded into f32 epilogue. Weights
// double-buffered through 2x32KB LDS (gl2lds w=16, XOR-swizzled src),
// prefetched 1 chunk ahead, 1 barrier/chunk. LDS 142KB -> 1 block/CU, 8 waves.
// Workspace:
//   xb   [16384][256] bf16 @ 0
//   w1t  [8][256][256] bf16 @ 8388608   (w1t[e][h][c] = W1[e][c][h])
//   wg1t [128][256] bf16 @ 9437184      (wg1t[h][c] = Wg1[c][h])
//   w2t  [256][2048] bf16 @ 9502720     (w2t[d][e*256+h] = W2[e][h][d])
//   g    [16384][8] f32 @ 10584064

typedef unsigned short USH;
typedef float f32x4 __attribute__((ext_vector_type(4)));
typedef __bf16 bf16x8 __attribute__((ext_vector_type(8)));

#define AS1 __attribute__((address_space(1)))
#define AS3 __attribute__((address_space(3)))

__device__ __forceinline__ USH f2bf(float f) {
  unsigned int u = __float_as_uint(f);
  u += 0x7fffu + ((u >> 16) & 1u);   // RNE
  return (USH)(u >> 16);
}

__device__ __forceinline__ void gl2lds16(const void* g, void* l) {
  __builtin_amdgcn_global_load_lds((AS1 const void*)g, (AS3 void*)l, 16, 0, 0);
}

// ---------------- prep ----------------

__global__ __launch_bounds__(256) void k_prep(
    const float* __restrict__ x,
    const float* __restrict__ Wg1,
    const float* __restrict__ W1,
    const float* __restrict__ W2,
    USH* __restrict__ xb, USH* __restrict__ wg1t,
    USH* __restrict__ w1t, USH* __restrict__ w2t) {
  __shared__ float T[64][65];
  int b = blockIdx.x, tid = threadIdx.x;

  if (b < 2048) {               // xb: flat coalesced cast
    size_t i8 = ((size_t)b * 256 + tid) * 8;
    float4 a = *(const float4*)(x + i8);
    float4 c = *(const float4*)(x + i8 + 4);
    USH v[8];
    v[0] = f2bf(a.x); v[1] = f2bf(a.y); v[2] = f2bf(a.z); v[3] = f2bf(a.w);
    v[4] = f2bf(c.x); v[5] = f2bf(c.y); v[6] = f2bf(c.z); v[7] = f2bf(c.w);
    *(uint4*)(xb + i8) = *(const uint4*)v;
  } else if (b < 2176) {        // w1t[e][h][c] = W1[e][c][h]
    int bp = b - 2048;
    int e = bp >> 4, tl = bp & 15;
    int c0 = (tl >> 2) * 64, h0 = (tl & 3) * 64;
    const float* src = W1 + (size_t)e * 65536;
#pragma unroll
    for (int p = 0; p < 4; ++p) {
      int r = p * 16 + (tid >> 4), d4 = (tid & 15) * 4;
      float4 v = *(const float4*)(src + (size_t)(c0 + r) * 256 + h0 + d4);
      T[r][d4] = v.x; T[r][d4 + 1] = v.y; T[r][d4 + 2] = v.z; T[r][d4 + 3] = v.w;
    }
    __syncthreads();
#pragma unroll
    for (int p = 0; p < 4; ++p) {
      int hr = p * 16 + (tid >> 4), c4 = (tid & 15) * 4;
      USH w[4];
#pragma unroll
      for (int j = 0; j < 4; ++j) w[j] = f2bf(T[c4 + j][hr]);
      *(uint2*)(w1t + (size_t)e * 65536 + (size_t)(h0 + hr) * 256 + c0 + c4) = *(const uint2*)w;
    }
  } else if (b < 2184) {        // wg1t[h][c] = Wg1[c][h]
    int bp = b - 2176;
    int c0 = (bp >> 1) * 64, h0 = (bp & 1) * 64;
#pragma unroll
    for (int p = 0; p < 4; ++p) {
      int r = p * 16 + (tid >> 4), d4 = (tid & 15) * 4;
      float4 v = *(const float4*)(Wg1 + (size_t)(c0 + r) * 128 + h0 + d4);
      T[r][d4] = v.x; T[r][d4 + 1] = v.y; T[r][d4 + 2] = v.z; T[r][d4 + 3] = v.w;
    }
    __syncthreads();
#pragma unroll
    for (int p = 0; p < 4; ++p) {
      int hr = p * 16 + (tid >> 4), c4 = (tid & 15) * 4;
      USH w[4];
#pragma unroll
      for (int j = 0; j < 4; ++j) w[j] = f2bf(T[c4 + j][hr]);
      *(uint2*)(wg1t + (size_t)(h0 + hr) * 256 + c0 + c4) = *(const uint2*)w;
    }
  } else {                      // w2t[d][e*256+h] = W2[e][h][d]
    int bp = b - 2184;
    int e = bp >> 4, tl = bp & 15;
    int h0 = (tl >> 2) * 64, d0 = (tl & 3) * 64;
    const float* src = W2 + (size_t)e * 65536;
#pragma unroll
    for (int p = 0; p < 4; ++p) {
      int r = p * 16 + (tid >> 4), d4 = (tid & 15) * 4;
      float4 v = *(const float4*)(src + (size_t)(h0 + r) * 256 + d0 + d4);
      T[r][d4] = v.x; T[r][d4 + 1] = v.y; T[r][d4 + 2] = v.z; T[r][d4 + 3] = v.w;
    }
    __syncthreads();
#pragma unroll
    for (int p = 0; p < 4; ++p) {
      int dr = p * 16 + (tid >> 4), h4 = (tid & 15) * 4;
      USH w[4];
#pragma unroll
      for (int j = 0; j < 4; ++j) w[j] = f2bf(T[h4 + j][dr]);
      *(uint2*)(w2t + (size_t)(d0 + dr) * 2048 + e * 256 + h0 + h4) = *(const uint2*)w;
    }
  }
}

// ---------------- gate (512 blocks x 32 rows, BK=64, swizzled) ----------------

__global__ __launch_bounds__(256) void k_gate(const USH* __restrict__ xb,
                                              const USH* __restrict__ wg1t,
                                              const float* __restrict__ bg1,
                                              const float* __restrict__ wg2,
                                              const float* __restrict__ bg2,
                                              float* __restrict__ g) {
  __shared__ __align__(16) USH As[32 * 64];
  __shared__ __align__(16) USH Bs[128 * 64];
  __shared__ float hg[32 * 129];
  __shared__ float bg1s[128];
  __shared__ float w2s[128 * 8];
  __shared__ float b2s[8];
  __shared__ float lg[32 * 8];

  int tid = threadIdx.x;
  int wave = tid >> 6, lane = tid & 63;
  int quad = lane >> 4, l16 = lane & 15;
  int sw = l16 & 7;
  int wr = wave >> 1, wc = wave & 1;
  int rowBase = blockIdx.x * 32;

  for (int t = tid; t < 1024; t += 256) w2s[t] = wg2[t];
  if (tid < 8) b2s[tid] = bg2[tid];
  if (tid < 128) bg1s[tid] = bg1[tid];

  f32x4 acc[4] = {};
  for (int kt = 0; kt < 4; ++kt) {
    int kb = kt * 64;
    {
      int r = tid >> 3, c8 = (tid & 7) ^ (r & 7);
      gl2lds16(xb + (size_t)(rowBase + r) * 256 + kb + c8 * 8, As + (size_t)tid * 8);
    }
#pragma unroll
    for (int c = 0; c < 4; ++c) {
      int i = c * 256 + tid;
      int r = i >> 3, c8 = (i & 7) ^ (r & 7);
      gl2lds16(wg1t + (size_t)r * 256 + kb + c8 * 8, Bs + (size_t)i * 8);
    }
    __syncthreads();
#pragma unroll
    for (int kkc = 0; kkc < 8; kkc += 4) {
      bf16x8 av = *(const bf16x8*)(As + (wr * 16 + l16) * 64 + (((kkc + quad) ^ sw) * 8));
#pragma unroll
      for (int j = 0; j < 4; ++j) {
        bf16x8 bv = *(const bf16x8*)(Bs + (wc * 64 + j * 16 + l16) * 64 + (((kkc + quad) ^ sw) * 8));
        acc[j] = __builtin_amdgcn_mfma_f32_16x16x32_bf16(av, bv, acc[j], 0, 0, 0);
      }
    }
    __syncthreads();
  }

#pragma unroll
  for (int j = 0; j < 4; ++j)
#pragma unroll
    for (int r = 0; r < 4; ++r) {
      int row = wr * 16 + quad * 4 + r;
      int col = wc * 64 + j * 16 + l16;
      hg[row * 129 + col] = fmaxf(acc[j][r] + bg1s[col], 0.0f);
    }
  __syncthreads();

  {
    int row = tid >> 3, p = tid & 7;
    float s = b2s[p];
    for (int k = 0; k < 128; ++k) s += hg[row * 129 + k] * w2s[k * 8 + p];
    lg[row * 8 + p] = s;
  }
  __syncthreads();

  if (tid < 32) {
    float l[8];
    float m = -1e30f;
#pragma unroll
    for (int e = 0; e < 8; ++e) { l[e] = lg[tid * 8 + e]; m = fmaxf(m, l[e]); }
    float s = 0.0f;
#pragma unroll
    for (int e = 0; e < 8; ++e) { l[e] = expf(l[e] - m); s += l[e]; }
    float inv = 1.0f / s;
    size_t grow = rowBase + tid;
#pragma unroll
    for (int e = 0; e < 8; ++e) g[grow * 8 + e] = l[e] * inv;
  }
}

// ---------------- fused experts (256 blocks x 64 rows, 512 thr) --------------

__global__ __launch_bounds__(512) void k_moe(const USH* __restrict__ xb,
                                             const USH* __restrict__ w1t,
                                             const USH* __restrict__ w2t,
                                             const float* __restrict__ b1,
                                             const float* __restrict__ b2,
                                             const float* __restrict__ g,
                                             float* __restrict__ out) {
  __shared__ __align__(16) USH xs[4 * 64 * 64];   // 32KB: [kt][r][slot*8+..] swizzled
  __shared__ __align__(16) USH Hs[64 * 256];      // 32KB: [n][ht*64+slot*8+..] swizzled
  __shared__ __align__(16) USH Ws[2][256 * 64];   // 64KB: weight staging, swizzled
  __shared__ float b1s[256];
  __shared__ float b2s[2048];
  __shared__ float gs[512];                       // gs[n*8+e]

  int tid = threadIdx.x;
  int wave = tid >> 6, lane = tid & 63;
  int quad = lane >> 4, l16 = lane & 15;
  int sw = l16 & 7;
  int rowBase = blockIdx.x * 64;

  // one-time: x tile (64 rows x 256 cols), swizzled per 64-col subtile
#pragma unroll
  for (int it = 0; it < 4; ++it) {
    int i = it * 512 + tid;
    int kt = i >> 9, rem = i & 511;
    int r = rem >> 3, slot = rem & 7;
    int c8 = slot ^ (r & 7);
    gl2lds16(xb + (size_t)(rowBase + r) * 256 + kt * 64 + c8 * 8, xs + (size_t)i * 8);
  }
#pragma unroll
  for (int t = tid; t < 2048; t += 512) b2s[t] = b2[t];
  gs[tid] = g[(size_t)rowBase * 8 + tid];

  // chunk T in [0,64): e=T>>3; T&4: 0 = W1 c-chunk, 1 = W2 h-chunk; (T&3)*64 = offset
  auto STAGE = [&](int T, int bf) {
    int e = T >> 3;
    int cb = (T & 3) * 64;
    const USH* src;
    size_t stride;
    if (T & 4) { src = w2t + e * 256 + cb;               stride = 2048; }
    else       { src = w1t + (size_t)e * 65536 + cb;     stride = 256;  }
    USH* dst = &Ws[bf][0];
#pragma unroll
    for (int it = 0; it < 4; ++it) {
      int i = it * 512 + tid;
      int r = i >> 3, slot = i & 7;
      int c8 = slot ^ (r & 7);
      gl2lds16(src + (size_t)r * stride + c8 * 8, dst + (size_t)i * 8);
    }
  };

  int wh = wave >> 1, wn = wave & 1;    // phase-1: wave = 64h x 32n
  int wn2 = wave >> 2, wd = wave & 3;   // phase-2: wave = 32n x 64d

  f32x4 oacc[2][4] = {};
  int buf = 0;
  STAGE(0, 0);

#pragma unroll 1
  for (int e = 0; e < 8; ++e) {
    f32x4 hacc[4][2] = {};
    if (tid < 256) b1s[tid] = b1[e * 256 + tid];

    // phase 1: H^T[h,n] = sum_c W1[c,h] * x[n,c]
    for (int kt = 0; kt < 4; ++kt) {
      __syncthreads();                        // Ws[buf] ready; prev reads of Ws[buf^1] done
      int T = e * 8 + kt;
      if (T < 63) STAGE(T + 1, buf ^ 1);
      const USH* W = &Ws[buf][0];
#pragma unroll
      for (int kkc = 0; kkc < 8; kkc += 4) {
        int cs = ((kkc + quad) ^ sw) * 8;
        bf16x8 av[4], bv[2];
#pragma unroll
        for (int i = 0; i < 4; ++i)
          av[i] = *(const bf16x8*)(W + (wh * 64 + i * 16 + l16) * 64 + cs);
#pragma unroll
        for (int j = 0; j < 2; ++j)
          bv[j] = *(const bf16x8*)(xs + kt * 4096 + (wn * 32 + j * 16 + l16) * 64 + cs);
#pragma unroll
        for (int i = 0; i < 4; ++i)
#pragma unroll
          for (int j = 0; j < 2; ++j)
            hacc[i][j] = __builtin_amdgcn_mfma_f32_16x16x32_bf16(av[i], bv[j], hacc[i][j], 0, 0, 0);
      }
      buf ^= 1;
    }

    // epilogue: Hs[n][h] = bf16(relu(hacc+b1)*g[n,e]); C[h,n]: 4 consecutive h
    // per reg quad -> ds_write_b64, directly in phase-2 A-frag layout.
#pragma unroll
    for (int i = 0; i < 4; ++i) {
      int c8 = i * 2 + (quad >> 1);
      int hb = wh * 64 + i * 16 + quad * 4;
#pragma unroll
      for (int j = 0; j < 2; ++j) {
        int n = wn * 32 + j * 16 + l16;
        float gg = gs[n * 8 + e];
        USH w4[4];
#pragma unroll
        for (int r = 0; r < 4; ++r)
          w4[r] = f2bf(fmaxf(hacc[i][j][r] + b1s[hb + r], 0.0f) * gg);
        int off = n * 256 + wh * 64 + (c8 ^ (n & 7)) * 8 + (quad & 1) * 4;
        *(uint2*)(Hs + off) = *(const uint2*)w4;
      }
    }

    // phase 2: out[n,d] += sum_h Hs[n,h] * W2[h,d]
    for (int ht = 0; ht < 4; ++ht) {
      __syncthreads();                        // Hs writes visible (ht=0); Ws[buf] ready
      int T = e * 8 + 4 + ht;
      if (T < 63) STAGE(T + 1, buf ^ 1);
      const USH* W = &Ws[buf][0];
#pragma unroll
      for (int kkc = 0; kkc < 8; kkc += 4) {
        int cs = ((kkc + quad) ^ sw) * 8;
        bf16x8 av[2], bv[4];
#pragma unroll
        for (int i = 0; i < 2; ++i)
          av[i] = *(const bf16x8*)(Hs + (wn2 * 32 + i * 16 + l16) * 256 + ht * 64 + cs);
#pragma unroll
        for (int j = 0; j < 4; ++j)
          bv[j] = *(const bf16x8*)(W + (wd * 64 + j * 16 + l16) * 64 + cs);
#pragma unroll
        for (int i = 0; i < 2; ++i)
#pragma unroll
          for (int j = 0; j < 4; ++j)
            oacc[i][j] = __builtin_amdgcn_mfma_f32_16x16x32_bf16(av[i], bv[j], oacc[i][j], 0, 0, 0);
      }
      buf ^= 1;
    }
  }

  // final epilogue: out = oacc + sum_e g[n,e]*b2[e,d]  (exact f32 bias)
#pragma unroll
  for (int i = 0; i < 2; ++i)
#pragma unroll
    for (int r = 0; r < 4; ++r) {
      int n = wn2 * 32 + i * 16 + quad * 4 + r;
      const float* gr = gs + n * 8;
      size_t grow = (size_t)(rowBase + n) * 256;
#pragma unroll
      for (int j = 0; j < 4; ++j) {
        int d = wd * 64 + j * 16 + l16;
        float bias = 0.0f;
#pragma unroll
        for (int ee = 0; ee < 8; ++ee) bias += gr[ee] * b2s[ee * 256 + d];
        out[grow + d] = oacc[i][j][r] + bias;
      }
    }
}

// ---------------- launch ----------------

extern "C" void kernel_launch(void* const* d_in, const int* in_sizes, int n_in,
                              void* d_out, int out_size, void* d_ws, size_t ws_size,
                              hipStream_t stream) {
  const float* x   = (const float*)d_in[0];
  const float* Wg1 = (const float*)d_in[1];
  const float* bg1 = (const float*)d_in[2];
  const float* Wg2 = (const float*)d_in[3];
  const float* bg2 = (const float*)d_in[4];
  const float* W1  = (const float*)d_in[5];
  const float* b1  = (const float*)d_in[6];
  const float* W2  = (const float*)d_in[7];
  const float* b2  = (const float*)d_in[8];
  float* out = (float*)d_out;

  char* ws = (char*)d_ws;
  USH*   xb   = (USH*)(ws);
  USH*   w1t  = (USH*)(ws + 8388608);
  USH*   wg1t = (USH*)(ws + 9437184);
  USH*   w2t  = (USH*)(ws + 9502720);
  float* g    = (float*)(ws + 10584064);

  hipLaunchKernelGGL(k_prep, dim3(2312), dim3(256), 0, stream,
                     x, Wg1, W1, W2, xb, wg1t, w1t, w2t);
  hipLaunchKernelGGL(k_gate, dim3(512), dim3(256), 0, stream,
                     xb, wg1t, bg1, Wg2, bg2, g);
  hipLaunchKernelGGL(k_moe, dim3(256), dim3(512), 0, stream,
                     xb, w1t, w2t, b1, b2, g, out);
}